// Round 1
// baseline (60.753 us; speedup 1.0000x reference)
//
#include <hip/hip_runtime.h>
#include <hip/hip_bf16.h>

typedef __attribute__((ext_vector_type(4))) float f32x4;
typedef __attribute__((ext_vector_type(8))) short s16x8;

#define NB 8
#define NC 16
#define HH 512
#define WW 512
// l = Hp*64 + Wp (4096), l' = hp*8 + wp (64), m = c*64 + kh*8 + kw (1024)

// ---------------- K1: 8x8 avg-pool -> B^T bf16 [b][m][l'] ----------------
__global__ __launch_bounds__(256) void pool_to_bt(const float* __restrict__ x,
                                                  __hip_bfloat16* __restrict__ bt) {
    int flat = blockIdx.x * 256 + threadIdx.x;      // 8*16*64*64 = 524288
    int wq = flat & 63;                             // pooled col w' (lane-consecutive -> coalesced)
    int hq = (flat >> 6) & 63;                      // pooled row h'
    int c  = (flat >> 12) & 15;
    int b  = flat >> 16;
    const float* base = x + ((size_t)(b * NC + c) * HH + hq * 8) * WW + wq * 8;
    float s = 0.f;
#pragma unroll
    for (int r = 0; r < 8; ++r) {
        f32x4 v0 = *(const f32x4*)(base + (size_t)r * WW);
        f32x4 v1 = *(const f32x4*)(base + (size_t)r * WW + 4);
        s += v0[0] + v0[1] + v0[2] + v0[3] + v1[0] + v1[1] + v1[2] + v1[3];
    }
    s *= (1.f / 64.f);
    int m  = c * 64 + (hq & 7) * 8 + (wq & 7);      // (c, kh, kw)
    int lp = (hq >> 3) * 8 + (wq >> 3);             // (hp, wp)
    bt[((size_t)b * 1024 + m) * 64 + lp] = __float2bfloat16(s);
}

// ------------- K1b: attn -> bf16(attn * 1/(nnz+1e-5)) [b][l][64] -------------
__global__ __launch_bounds__(256) void attn_prep(const float* __restrict__ attn,
                                                 __hip_bfloat16* __restrict__ abf) {
    int row  = blockIdx.x * 4 + (threadIdx.x >> 6);  // 8*4096 = 32768 rows, 1 wave/row
    int lane = threadIdx.x & 63;
    float v = attn[(size_t)row * 64 + lane];
    unsigned long long nzmask = __ballot(v != 0.0f);
    float inv = 1.0f / ((float)__popcll(nzmask) + 1e-5f);
    abf[(size_t)row * 64 + lane] = __float2bfloat16(v * inv);
}

// ------------- K2: Out[l,m] = A[l,:] * B[:,m], scatter-Fold to out -------------
#define BM 128
#define BN 128
#define LDK 72   // 64 + 8 bf16 pad (144B pitch, 16B aligned, breaks bank conflicts)

__global__ __launch_bounds__(256) void gemm_scatter(const __hip_bfloat16* __restrict__ abf,
                                                    const __hip_bfloat16* __restrict__ bt,
                                                    float* __restrict__ out) {
    int mb = blockIdx.x;     // 0..7   m-tile
    int lb = blockIdx.y;     // 0..31  l-tile
    int b  = blockIdx.z;     // 0..7

    __shared__ __align__(16) unsigned short As[BM][LDK];
    __shared__ __align__(16) unsigned short Bs[BN][LDK];

    int tid = threadIdx.x;
    const unsigned short* Ag = (const unsigned short*)abf + ((size_t)b * 4096 + lb * BM) * 64;
    const unsigned short* Bg = (const unsigned short*)bt  + ((size_t)b * 1024 + mb * BN) * 64;
#pragma unroll
    for (int i = 0; i < 4; ++i) {                   // 1024 chunks of 16B, coalesced
        int cid = tid + i * 256;
        int row = cid >> 3, c8 = cid & 7;
        *(s16x8*)&As[row][c8 * 8] = *(const s16x8*)(Ag + row * 64 + c8 * 8);
    }
#pragma unroll
    for (int i = 0; i < 4; ++i) {
        int cid = tid + i * 256;
        int row = cid >> 3, c8 = cid & 7;
        *(s16x8*)&Bs[row][c8 * 8] = *(const s16x8*)(Bg + row * 64 + c8 * 8);
    }
    __syncthreads();

    int w    = tid >> 6;
    int lane = tid & 63;
    int wl   = (w >> 1) * 64;     // wave l-base in tile
    int wm   = (w & 1) * 64;      // wave m-base in tile
    int lr   = lane & 15;
    int kq   = lane >> 4;

    f32x4 acc[4][4] = {};
#pragma unroll
    for (int ks = 0; ks < 2; ++ks) {                // K = 64 = 2 x 32
        s16x8 af[4], bfr[4];
#pragma unroll
        for (int i = 0; i < 4; ++i)
            af[i] = *(const s16x8*)&As[wl + i * 16 + lr][ks * 32 + kq * 8];
#pragma unroll
        for (int j = 0; j < 4; ++j)
            bfr[j] = *(const s16x8*)&Bs[wm + j * 16 + lr][ks * 32 + kq * 8];
#pragma unroll
        for (int i = 0; i < 4; ++i)
#pragma unroll
            for (int j = 0; j < 4; ++j)
                acc[i][j] = __builtin_amdgcn_mfma_f32_16x16x32_bf16(af[i], bfr[j], acc[i][j], 0, 0, 0);
    }

    // epilogue: C/D layout col = lane&15, row = (lane>>4)*4 + j  (m89-verified)
#pragma unroll
    for (int i = 0; i < 4; ++i) {
#pragma unroll
        for (int jf = 0; jf < 4; ++jf) {
            int m  = mb * BN + wm + jf * 16 + lr;
            int c  = m >> 6, kh = (m >> 3) & 7, kw = m & 7;
#pragma unroll
            for (int j = 0; j < 4; ++j) {
                int l  = lb * BM + wl + i * 16 + kq * 4 + j;
                int Hp = l >> 6, Wp = l & 63;
                out[(((size_t)(b * NC + c) * HH) + Hp * 8 + kh) * WW + Wp * 8 + kw] = acc[i][jf][j];
            }
        }
    }
}

extern "C" void kernel_launch(void* const* d_in, const int* in_sizes, int n_in,
                              void* d_out, int out_size, void* d_ws, size_t ws_size,
                              hipStream_t stream) {
    const float* x    = (const float*)d_in[0];
    const float* attn = (const float*)d_in[1];
    float* out        = (float*)d_out;

    __hip_bfloat16* bt  = (__hip_bfloat16*)d_ws;                        // 1 MB:  [8][1024][64]
    __hip_bfloat16* abf = (__hip_bfloat16*)((char*)d_ws + (1 << 20));   // 4 MB:  [8][4096][64]

    pool_to_bt<<<2048, 256, 0, stream>>>(x, bt);
    attn_prep<<<8192, 256, 0, stream>>>(attn, abf);
    dim3 grid(8, 32, 8);
    gemm_scatter<<<grid, 256, 0, stream>>>(abf, bt, out);
}

// Round 2
// 56.751 us; speedup vs baseline: 1.0705x; 1.0705x over previous
//
#include <hip/hip_runtime.h>
#include <hip/hip_bf16.h>

typedef __attribute__((ext_vector_type(4))) float f32x4;
typedef __attribute__((ext_vector_type(8))) short s16x8;

#define NB 8
#define NC 16
#define HH 512
#define WW 512
// l = Hp*64 + Wp (4096), l' = hp*8 + wp (64), m = c*64 + kh*8 + kw (1024)

// ---------------- K1: 8x8 avg-pool -> B^T bf16 [b][m][l'] ----------------
__global__ __launch_bounds__(256) void pool_to_bt(const float* __restrict__ x,
                                                  __hip_bfloat16* __restrict__ bt) {
    int flat = blockIdx.x * 256 + threadIdx.x;      // 8*16*64*64 = 524288
    int wq = flat & 63;                             // pooled col w' (lane-consecutive -> coalesced)
    int hq = (flat >> 6) & 63;                      // pooled row h'
    int c  = (flat >> 12) & 15;
    int b  = flat >> 16;
    const float* base = x + ((size_t)(b * NC + c) * HH + hq * 8) * WW + wq * 8;
    float s = 0.f;
#pragma unroll
    for (int r = 0; r < 8; ++r) {
        f32x4 v0 = *(const f32x4*)(base + (size_t)r * WW);
        f32x4 v1 = *(const f32x4*)(base + (size_t)r * WW + 4);
        s += v0[0] + v0[1] + v0[2] + v0[3] + v1[0] + v1[1] + v1[2] + v1[3];
    }
    s *= (1.f / 64.f);
    int m  = c * 64 + (hq & 7) * 8 + (wq & 7);      // (c, kh, kw)
    int lp = (hq >> 3) * 8 + (wq >> 3);             // (hp, wp)
    bt[((size_t)b * 1024 + m) * 64 + lp] = __float2bfloat16(s);
}

// ------------- K2: Out[l,m] = attn_norm[l,:] * Bt[m,:], fold-scatter -------------
// MFMA operand roles: A-operand rows = m (from Bs), B-operand rows = l (from As).
// => D col (lane&15) indexes l, D row ((lane>>4)*4+r) indexes m. Per-thread acc
// regs run along m => along kw => f32x4 store of 4 consecutive output floats.
#define BM 128   // l per block
#define BN 128   // m per block
#define LDK 72   // 64 + 8 bf16 pad (144B pitch, 16B aligned)

__global__ __launch_bounds__(256) void gemm_scatter(const float* __restrict__ attn,
                                                    const __hip_bfloat16* __restrict__ bt,
                                                    float* __restrict__ out) {
    int mb = blockIdx.x;     // 0..7   m-tile
    int lb = blockIdx.y;     // 0..31  l-tile
    int b  = blockIdx.z;     // 0..7

    __shared__ __align__(16) unsigned short As[BM][LDK];   // attn_norm bf16 [l][k]
    __shared__ __align__(16) unsigned short Bs[BN][LDK];   // bt bf16        [m][k]

    int tid = threadIdx.x;

    // --- stage A: raw f32 attn -> normalize -> bf16 LDS (2 threads per row) ---
    {
        int row  = tid >> 1;     // 0..127
        int half = tid & 1;      // which 32-float half
        const float* Arow = attn + ((size_t)(b * 4096 + lb * BM + row)) * 64 + half * 32;
        f32x4 v[8];
        int cnt = 0;
#pragma unroll
        for (int j = 0; j < 8; ++j) {
            v[j] = *(const f32x4*)(Arow + j * 4);
            cnt += (v[j][0] != 0.f) + (v[j][1] != 0.f) + (v[j][2] != 0.f) + (v[j][3] != 0.f);
        }
        cnt += __shfl_xor(cnt, 1);
        float inv = 1.0f / ((float)cnt + 1e-5f);
#pragma unroll
        for (int j = 0; j < 4; ++j) {
            s16x8 o;
#pragma unroll
            for (int e = 0; e < 8; ++e) {
                __hip_bfloat16 h = __float2bfloat16(v[j * 2 + (e >> 2)][e & 3] * inv);
                o[e] = (short)*reinterpret_cast<unsigned short*>(&h);
            }
            *(s16x8*)&As[row][half * 32 + j * 8] = o;
        }
    }
    // --- stage B: bt tile, coalesced 16B chunks ---
    {
        const unsigned short* Bg = (const unsigned short*)bt + ((size_t)b * 1024 + mb * BN) * 64;
#pragma unroll
        for (int i = 0; i < 4; ++i) {
            int cid = tid + i * 256;
            int row = cid >> 3, c8 = cid & 7;
            *(s16x8*)&Bs[row][c8 * 8] = *(const s16x8*)(Bg + row * 64 + c8 * 8);
        }
    }
    __syncthreads();

    int w    = tid >> 6;
    int lane = tid & 63;
    int wm   = (w & 1) * 64;      // wave m-base in tile
    int wl   = (w >> 1) * 64;     // wave l-base in tile
    int lr   = lane & 15;
    int kq   = lane >> 4;

    f32x4 acc[4][4] = {};         // [mi][lj]
#pragma unroll
    for (int ks = 0; ks < 2; ++ks) {                // K = 64 = 2 x 32
        s16x8 mf[4], lf[4];
#pragma unroll
        for (int i = 0; i < 4; ++i)
            mf[i] = *(const s16x8*)&Bs[wm + i * 16 + lr][ks * 32 + kq * 8];
#pragma unroll
        for (int j = 0; j < 4; ++j)
            lf[j] = *(const s16x8*)&As[wl + j * 16 + lr][ks * 32 + kq * 8];
#pragma unroll
        for (int i = 0; i < 4; ++i)
#pragma unroll
            for (int j = 0; j < 4; ++j)
                acc[i][j] = __builtin_amdgcn_mfma_f32_16x16x32_bf16(mf[i], lf[j], acc[i][j], 0, 0, 0);
    }

    // --- epilogue: f32x4 stores; 4 consecutive m == 4 consecutive kw ---
#pragma unroll
    for (int mi = 0; mi < 4; ++mi) {
        int m0 = mb * BN + wm + mi * 16 + kq * 4;   // multiple of 4
        int c  = m0 >> 6, kh = (m0 >> 3) & 7, kw = m0 & 7;   // kw in {0,4}
        float* obase = out + (((size_t)(b * NC + c) * HH) + kh) * WW + kw;
#pragma unroll
        for (int lj = 0; lj < 4; ++lj) {
            int l  = lb * BM + wl + lj * 16 + lr;
            int Hp = l >> 6, Wp = l & 63;
            *(f32x4*)(obase + ((size_t)Hp * 8) * WW + Wp * 8) = acc[mi][lj];
        }
    }
}

extern "C" void kernel_launch(void* const* d_in, const int* in_sizes, int n_in,
                              void* d_out, int out_size, void* d_ws, size_t ws_size,
                              hipStream_t stream) {
    const float* x    = (const float*)d_in[0];
    const float* attn = (const float*)d_in[1];
    float* out        = (float*)d_out;

    __hip_bfloat16* bt = (__hip_bfloat16*)d_ws;     // 1 MB: [8][1024][64]

    pool_to_bt<<<2048, 256, 0, stream>>>(x, bt);
    dim3 grid(8, 32, 8);
    gemm_scatter<<<grid, 256, 0, stream>>>(attn, bt, out);
}